// Round 2
// baseline (1041.440 us; speedup 1.0000x reference)
//
#include <hip/hip_runtime.h>
#include <math.h>

#define EMB     128
#define ATTR    16
#define KDIM    (2*EMB + ATTR)   // 272
#define HID     64
#define TILE    64               // edges per block
#define XSTRIDE 273              // odd stride => conflict-free per-lane column reads

__global__ __launch_bounds__(256, 2)
void edge_mlp_kernel(const float* __restrict__ z,
                     const int*   __restrict__ eidx,   // [2][E] (row0=src, row1=dst)
                     const float* __restrict__ attr,   // [E][16]
                     const float* __restrict__ W1,     // [272][64]
                     const float* __restrict__ b1,     // [64]
                     const float* __restrict__ W2,     // [64]
                     const float* __restrict__ b2,     // [1]
                     float*       __restrict__ out,    // [E]
                     int E, int n_nodes)
{
    __shared__ float xt[TILE * XSTRIDE];   // 69,888 B
    __shared__ float red[4][TILE];         //  1,024 B

    const int tid  = threadIdx.x;
    const int base = blockIdx.x * TILE;

    // ---- Stage x-tile into LDS: xt[e][0:128]=z[src], [128:256]=z[dst], [256:272]=attr
    // src+dst rows: 64 edges * 64 float4 (32 src + 32 dst) = 4096 float4, 16/thread.
    // Each wave stages one edge's two z-rows: 512 B contiguous per 32 lanes => coalesced.
    #pragma unroll
    for (int i = 0; i < 16; ++i) {
        int f   = tid + i * 256;      // 0..4095
        int e   = f >> 6;             // edge within tile
        int c   = f & 63;             // float4 slot within the edge's two rows
        int sel = c >> 5;             // 0 = src row, 1 = dst row
        int c4  = c & 31;             // float4 col within the z row
        int eg  = base + e;
        int idx = 0;
        if (eg < E) {
            idx = eidx[sel * E + eg];
            if (idx < 0 || idx >= n_nodes) idx = 0;   // defensive clamp
        }
        const float4* zp = reinterpret_cast<const float4*>(z + (size_t)idx * EMB);
        float4 v = zp[c4];
        float* dstp = &xt[e * XSTRIDE + sel * EMB + (c4 << 2)];
        dstp[0] = v.x; dstp[1] = v.y; dstp[2] = v.z; dstp[3] = v.w;
    }
    // attr: 64 edges * 4 float4 = 256 float4, 1/thread (1 KB contiguous per wave)
    {
        int e  = tid >> 2;
        int c4 = tid & 3;
        int eg = base + e;
        float4 v = make_float4(0.f, 0.f, 0.f, 0.f);
        if (eg < E) {
            const float4* ap = reinterpret_cast<const float4*>(attr + (size_t)eg * ATTR);
            v = ap[c4];
        }
        float* dstp = &xt[e * XSTRIDE + 2 * EMB + (c4 << 2)];
        dstp[0] = v.x; dstp[1] = v.y; dstp[2] = v.z; dstp[3] = v.w;
    }
    __syncthreads();

    // ---- MLP layer 1: lane = edge (64 edges), wave = 16-hidden slice.
    const int lane = tid & 63;
    const int w    = __builtin_amdgcn_readfirstlane(tid >> 6);  // wave id, provably uniform
    const int js   = w * 16;                                    // hidden-slice start

    float acc[16];
    #pragma unroll
    for (int jj = 0; jj < 16; ++jj) acc[jj] = 0.f;

    const float* __restrict__ xrow = xt + lane * XSTRIDE;

    #pragma unroll 4
    for (int k = 0; k < KDIM; ++k) {
        float xk = xrow[k];                               // ds_read_b32, 2-way bank alias (free)
        const float* __restrict__ wr = W1 + k * HID + js; // wave-uniform => s_load_dwordx4
        #pragma unroll
        for (int jj = 0; jj < 16; ++jj)
            acc[jj] = fmaf(xk, wr[jj], acc[jj]);          // v_fmac, SGPR weight operand
    }

    // ---- bias + relu + layer-2 partial dot (per-lane over this wave's 16 hidden)
    float p = 0.f;
    #pragma unroll
    for (int jj = 0; jj < 16; ++jj) {
        float h = acc[jj] + b1[js + jj];
        h = fmaxf(h, 0.f);
        p = fmaf(h, W2[js + jj], p);
    }
    red[w][lane] = p;
    __syncthreads();

    // ---- cross-wave reduce + sigmoid + coalesced store
    if (tid < TILE) {
        int eg = base + tid;
        if (eg < E) {
            float s = red[0][tid] + red[1][tid] + red[2][tid] + red[3][tid] + b2[0];
            out[eg] = 1.f / (1.f + expf(-s));
        }
    }
}

extern "C" void kernel_launch(void* const* d_in, const int* in_sizes, int n_in,
                              void* d_out, int out_size, void* d_ws, size_t ws_size,
                              hipStream_t stream)
{
    const float* z  = (const float*)d_in[0];
    const int*   ei = (const int*)  d_in[1];
    const float* ea = (const float*)d_in[2];
    const float* W1 = (const float*)d_in[3];
    const float* b1 = (const float*)d_in[4];
    const float* W2 = (const float*)d_in[5];
    const float* b2 = (const float*)d_in[6];
    float* out = (float*)d_out;

    const int E       = in_sizes[1] / 2;      // edge_index is [2][E]
    const int n_nodes = in_sizes[0] / EMB;

    const int grid = (E + TILE - 1) / TILE;
    hipLaunchKernelGGL(edge_mlp_kernel, dim3(grid), dim3(256), 0, stream,
                       z, ei, ea, W1, b1, W2, b2, out, E, n_nodes);
}

// Round 6
// 347.599 us; speedup vs baseline: 2.9961x; 2.9961x over previous
//
#include <hip/hip_runtime.h>
#include <math.h>

#define EMB   128
#define ATTR  16
#define KDIM  272
#define KPAD  288            // K padded to 9 * 32
#define HID   64
#define TILE  64             // edges per block
#define RS    320            // LDS row stride in ushorts (640 B = 5 x 128B windows)

typedef short s16x8 __attribute__((ext_vector_type(8)));
typedef float f32x4 __attribute__((ext_vector_type(4)));

union Frag { ushort s[8]; uint4 q; s16x8 v; };

static __device__ __forceinline__ ushort f2bf(float f) {
    union { float f; uint u; } v; v.f = f;
    uint u = v.u;
    return (ushort)((u + 0x7FFFu + ((u >> 16) & 1u)) >> 16);  // RNE
}

// ---- prep: w1t[j][k] = bf16(W1[k][j]), K zero-padded to 288 ----
__global__ void prep_w1t(const float* __restrict__ W1, ushort* __restrict__ w1t) {
    int idx = blockIdx.x * blockDim.x + threadIdx.x;   // 0 .. 64*288-1
    int j = idx / KPAD;
    int k = idx - j * KPAD;
    float v = (k < KDIM) ? W1[k * HID + j] : 0.f;
    w1t[idx] = f2bf(v);
}

__global__ __launch_bounds__(256, 4)
void edge_mlp_mfma(const float* __restrict__ z,
                   const int*   __restrict__ eidx,   // [2][E]
                   const float* __restrict__ attr,   // [E][16]
                   const ushort* __restrict__ w1t,   // [64][288] bf16
                   const float* __restrict__ b1,     // [64]
                   const float* __restrict__ w2,     // [64]
                   const float* __restrict__ b2,     // [1]
                   float*       __restrict__ out,    // [E]
                   int E, int n_nodes)
{
    __shared__ ushort xlds[TILE * RS];   // 40,960 B

    const int tid  = threadIdx.x;
    const int base = blockIdx.x * TILE;

    // ---- stage X tile as bf16, swizzled: row e, 16B-unit u at ((u*8) ^ ((e&7)<<3)) ushorts
    {
        const int e  = tid >> 2;          // 0..63 (4 threads per edge)
        const int eg = base + e;
        const bool valid = (eg < E);
        int si = 0, di = 0;
        if (valid) {
            si = eidx[eg];      if ((unsigned)si >= (unsigned)n_nodes) si = 0;
            di = eidx[E + eg];  if ((unsigned)di >= (unsigned)n_nodes) di = 0;
        }
        const float4* srcp = reinterpret_cast<const float4*>(z + (size_t)si * EMB);
        const float4* dstp = reinterpret_cast<const float4*>(z + (size_t)di * EMB);
        const float4* atp  = reinterpret_cast<const float4*>(attr + (size_t)eg * ATTR);
        const int u0 = tid & 3;
        #pragma unroll
        for (int i = 0; i < 9; ++i) {
            const int u = u0 + i * 4;     // 16B-unit index 0..35 (36 units = 288 bf16)
            float4 f0 = make_float4(0.f, 0.f, 0.f, 0.f), f1 = f0;
            if (valid) {
                if (u < 16)       { f0 = srcp[u * 2];        f1 = srcp[u * 2 + 1]; }
                else if (u < 32)  { f0 = dstp[(u-16) * 2];   f1 = dstp[(u-16) * 2 + 1]; }
                else if (u == 32) { f0 = atp[0];             f1 = atp[1]; }
                else if (u == 33) { f0 = atp[2];             f1 = atp[3]; }
                // u == 34, 35: zero pad (k = 272..287)
            }
            Frag pk;
            pk.s[0] = f2bf(f0.x); pk.s[1] = f2bf(f0.y);
            pk.s[2] = f2bf(f0.z); pk.s[3] = f2bf(f0.w);
            pk.s[4] = f2bf(f1.x); pk.s[5] = f2bf(f1.y);
            pk.s[6] = f2bf(f1.z); pk.s[7] = f2bf(f1.w);
            const int off = e * RS + ((u * 8) ^ ((e & 7) << 3));
            *reinterpret_cast<uint4*>(&xlds[off]) = pk.q;
        }
    }
    __syncthreads();

    // ---- MFMA: wave w owns edges [w*16, w*16+16), all 64 hidden (4 n-frags)
    const int lane  = tid & 63;
    const int w     = tid >> 6;
    const int m0    = w * 16;
    const int rl    = lane & 15;      // A row / B-D col within frag
    const int kh    = lane >> 4;      // k-half selector (0..3)

    f32x4 acc[4];
    #pragma unroll
    for (int nf = 0; nf < 4; ++nf) acc[nf] = (f32x4){0.f, 0.f, 0.f, 0.f};

    const int arow = m0 + rl;
    const ushort* __restrict__ xrow = xlds + arow * RS;
    const int swz = (arow & 7) << 3;  // ushort units (16 B)

    #pragma unroll
    for (int s = 0; s < 9; ++s) {
        Frag a;
        a.q = *reinterpret_cast<const uint4*>(&xrow[(s * 32 + kh * 8) ^ swz]);
        #pragma unroll
        for (int nf = 0; nf < 4; ++nf) {
            Frag b;
            b.q = *reinterpret_cast<const uint4*>(
                      w1t + (size_t)(nf * 16 + rl) * KPAD + s * 32 + kh * 8);
            acc[nf] = __builtin_amdgcn_mfma_f32_16x16x32_bf16(a.v, b.v, acc[nf], 0, 0, 0);
        }
    }

    // ---- epilogue: bias + relu + W2 dot (fp32), reduce over 16 cols, sigmoid
    float p[4] = {0.f, 0.f, 0.f, 0.f};
    #pragma unroll
    for (int nf = 0; nf < 4; ++nf) {
        const int j = nf * 16 + rl;
        const float bb = b1[j];
        const float ww = w2[j];
        #pragma unroll
        for (int r = 0; r < 4; ++r) {
            float h = acc[nf][r] + bb;
            h = fmaxf(h, 0.f);
            p[r] = fmaf(h, ww, p[r]);
        }
    }
    #pragma unroll
    for (int m = 1; m <= 8; m <<= 1) {
        #pragma unroll
        for (int r = 0; r < 4; ++r) p[r] += __shfl_xor(p[r], m, 64);
    }
    if (rl == 0) {
        const float bb2 = b2[0];
        const int ebase = base + m0 + kh * 4;   // D row = 4*kh + r
        #pragma unroll
        for (int r = 0; r < 4; ++r) {
            if (ebase + r < E) {
                const float sv = p[r] + bb2;
                out[ebase + r] = 1.f / (1.f + expf(-sv));
            }
        }
    }
}

extern "C" void kernel_launch(void* const* d_in, const int* in_sizes, int n_in,
                              void* d_out, int out_size, void* d_ws, size_t ws_size,
                              hipStream_t stream)
{
    const float* z  = (const float*)d_in[0];
    const int*   ei = (const int*)  d_in[1];
    const float* ea = (const float*)d_in[2];
    const float* W1 = (const float*)d_in[3];
    const float* b1 = (const float*)d_in[4];
    const float* W2 = (const float*)d_in[5];
    const float* b2 = (const float*)d_in[6];
    float* out = (float*)d_out;

    const int E       = in_sizes[1] / 2;     // edge_index is [2][E]
    const int n_nodes = in_sizes[0] / EMB;

    ushort* w1t = (ushort*)d_ws;             // 64*288*2 = 36,864 B

    hipLaunchKernelGGL(prep_w1t, dim3((HID * KPAD) / 256), dim3(256), 0, stream, W1, w1t);

    const int grid = (E + TILE - 1) / TILE;
    hipLaunchKernelGGL(edge_mlp_mfma, dim3(grid), dim3(256), 0, stream,
                       z, ei, ea, w1t, b1, W2, b2, out, E, n_nodes);
}